// Round 1
// baseline (723.656 us; speedup 1.0000x reference)
//
#include <hip/hip_runtime.h>
#include <hip/hip_bf16.h>
#include <math.h>

#define N_NODES 100000
#define N_EDGES 800000

__device__ __forceinline__ float lrelu(float v){ return v > 0.f ? v : 0.2f*v; }
__device__ __forceinline__ float eluf(float v){ return v > 0.f ? v : (__expf(v) - 1.f); }

// ---------- CSR build ----------
__global__ __launch_bounds__(256) void count_kernel(const int* __restrict__ ei, int* __restrict__ counts){
    int e = blockIdx.x*256 + threadIdx.x;
    if (e < N_EDGES) atomicAdd(&counts[ei[N_EDGES + e]], 1);
}

__global__ __launch_bounds__(1024) void scan_kernel(const int* __restrict__ counts,
                                                    int* __restrict__ offs, int* __restrict__ cursor){
    __shared__ int part[1024];
    int t = threadIdx.x;
    const int chunk = (N_NODES + 1023)/1024;
    int lo = t*chunk, hi = lo + chunk;
    if (lo > N_NODES) lo = N_NODES;
    if (hi > N_NODES) hi = N_NODES;
    int s = 0;
    for (int i = lo; i < hi; i++) s += counts[i];
    part[t] = s; __syncthreads();
    for (int off = 1; off < 1024; off <<= 1){
        int v = (t >= off) ? part[t-off] : 0;
        __syncthreads();
        part[t] += v;
        __syncthreads();
    }
    int run = (t == 0) ? 0 : part[t-1];
    for (int i = lo; i < hi; i++){ offs[i] = run; cursor[i] = run; run += counts[i]; }
    if (t == 1023) offs[N_NODES] = part[1023];
}

__global__ __launch_bounds__(256) void scatter_kernel(const int* __restrict__ ei,
                                                      int* __restrict__ cursor, int* __restrict__ csr_src){
    int e = blockIdx.x*256 + threadIdx.x;
    if (e < N_EDGES){
        int d = ei[N_EDGES + e];
        int slot = atomicAdd(&cursor[d], 1);
        csr_src[slot] = ei[e];
    }
}

// ---------- GEMM1: h1 = x @ W1  (+ fused alpha_src1/alpha_dst1) ----------
__global__ __launch_bounds__(256) void gemm1_kernel(
    const float* __restrict__ x, const float* __restrict__ W1,
    const float* __restrict__ a_src, const float* __restrict__ a_dst,
    float* __restrict__ h1, float* __restrict__ as1, float* __restrict__ ad1)
{
    __shared__ float Wl[128*128];
    __shared__ float Xl[32*128];
    int t = threadIdx.x;
    const float4* W4 = (const float4*)W1;
    float4* Wl4 = (float4*)Wl;
    for (int i = t; i < 4096; i += 256) Wl4[i] = W4[i];
    int row0 = blockIdx.x*32;
    const float4* X4 = (const float4*)(x + (size_t)row0*128);
    float4* Xl4 = (float4*)Xl;
    for (int i = t; i < 1024; i += 256) Xl4[i] = X4[i];
    __syncthreads();

    int tx = t & 31, ty = t >> 5;
    int c0 = tx*4;
    int rbase = ty*4;
    float4 acc[4];
    #pragma unroll
    for (int r = 0; r < 4; r++) acc[r] = float4{0.f,0.f,0.f,0.f};

    for (int k = 0; k < 128; k += 4){
        float4 xr[4];
        #pragma unroll
        for (int ri = 0; ri < 4; ri++) xr[ri] = *(const float4*)&Xl[(rbase+ri)*128 + k];
        #pragma unroll
        for (int kk = 0; kk < 4; kk++){
            float4 w = *(const float4*)&Wl[(k+kk)*128 + c0];
            #pragma unroll
            for (int ri = 0; ri < 4; ri++){
                float xv = (kk==0)?xr[ri].x:(kk==1)?xr[ri].y:(kk==2)?xr[ri].z:xr[ri].w;
                acc[ri].x += xv*w.x; acc[ri].y += xv*w.y; acc[ri].z += xv*w.z; acc[ri].w += xv*w.w;
            }
        }
    }
    #pragma unroll
    for (int ri = 0; ri < 4; ri++){
        int r = row0 + rbase + ri;
        *(float4*)&h1[(size_t)r*128 + c0] = acc[ri];
    }
    // fused alpha projections: a_src/a_dst are [8][16] flat = 128 entries; col index == c0+j
    int head = tx >> 2;
    #pragma unroll
    for (int ri = 0; ri < 4; ri++){
        float ps = acc[ri].x*a_src[c0] + acc[ri].y*a_src[c0+1] + acc[ri].z*a_src[c0+2] + acc[ri].w*a_src[c0+3];
        float pd = acc[ri].x*a_dst[c0] + acc[ri].y*a_dst[c0+1] + acc[ri].z*a_dst[c0+2] + acc[ri].w*a_dst[c0+3];
        ps += __shfl_xor(ps, 1); ps += __shfl_xor(ps, 2);
        pd += __shfl_xor(pd, 1); pd += __shfl_xor(pd, 2);
        if ((tx & 3) == 0){
            int r = row0 + rbase + ri;
            as1[r*8 + head] = ps;
            ad1[r*8 + head] = pd;
        }
    }
}

// ---------- agg layer1: one wave per dst node ----------
__global__ __launch_bounds__(256) void agg1_kernel(
    const int* __restrict__ offs, const int* __restrict__ csr_src,
    const float* __restrict__ as1, const float* __restrict__ ad1,
    const float* __restrict__ h1, const float* __restrict__ b1,
    float* __restrict__ emb1_out /* d_out + 1 */)
{
    int wave = threadIdx.x >> 6;
    int lane = threadIdx.x & 63;
    int d = blockIdx.x*4 + wave;
    if (d >= N_NODES) return;
    int h = lane >> 3;                 // head 0..7
    int col = 2*lane;                  // = h*16 + (lane&7)*2
    int e0 = offs[d], e1 = offs[d+1];
    float ad = ad1[d*8 + h];
    float acc0 = 0.f, acc1 = 0.f, wsum = 0.f;
    for (int i = e0; i < e1; i++){
        int s = csr_src[i];
        float w = __expf(lrelu(as1[s*8 + h] + ad));
        const float* hp = h1 + (size_t)s*128 + col;
        acc0 += w*hp[0]; acc1 += w*hp[1];
        wsum += w;
    }
    float inv = 1.f/(wsum + 1e-16f);
    emb1_out[(size_t)d*128 + col]     = acc0*inv + b1[col];
    emb1_out[(size_t)d*128 + col + 1] = acc1*inv + b1[col+1];
}

// ---------- GEMM2: h2 = elu(emb1) @ W2 (+ fused alpha_src2/alpha_dst2) ----------
__global__ __launch_bounds__(256) void gemm2_kernel(
    const float* __restrict__ emb1g /* d_out+1 */, const float* __restrict__ W2,
    const float* __restrict__ a_src2, const float* __restrict__ a_dst2,
    float* __restrict__ h2, float* __restrict__ as2, float* __restrict__ ad2)
{
    __shared__ float Wl[128*100];
    __shared__ float Xl[32*128];
    __shared__ float Hl[32*100];
    __shared__ float Al[200];
    int t = threadIdx.x;
    const float4* W4 = (const float4*)W2;
    float4* Wl4 = (float4*)Wl;
    for (int i = t; i < 3200; i += 256) Wl4[i] = W4[i];
    int row0 = blockIdx.x*32;
    for (int i = t; i < 4096; i += 256) Xl[i] = eluf(emb1g[(size_t)row0*128 + i]);
    if (t < 200) Al[t] = (t < 100) ? a_src2[t] : a_dst2[t-100];
    __syncthreads();

    int tx = t & 31, ty = t >> 5;
    int c0 = tx*4;
    bool active = (c0 < 100);
    int rbase = ty*4;
    float4 acc[4];
    #pragma unroll
    for (int r = 0; r < 4; r++) acc[r] = float4{0.f,0.f,0.f,0.f};

    if (active){
        for (int k = 0; k < 128; k += 4){
            float4 xr[4];
            #pragma unroll
            for (int ri = 0; ri < 4; ri++) xr[ri] = *(const float4*)&Xl[(rbase+ri)*128 + k];
            #pragma unroll
            for (int kk = 0; kk < 4; kk++){
                float4 w = *(const float4*)&Wl[(k+kk)*100 + c0];
                #pragma unroll
                for (int ri = 0; ri < 4; ri++){
                    float xv = (kk==0)?xr[ri].x:(kk==1)?xr[ri].y:(kk==2)?xr[ri].z:xr[ri].w;
                    acc[ri].x += xv*w.x; acc[ri].y += xv*w.y; acc[ri].z += xv*w.z; acc[ri].w += xv*w.w;
                }
            }
        }
        #pragma unroll
        for (int ri = 0; ri < 4; ri++){
            int r = row0 + rbase + ri;
            *(float4*)&h2[(size_t)r*100 + c0] = acc[ri];
            *(float4*)&Hl[(rbase+ri)*100 + c0] = acc[ri];
        }
    }
    __syncthreads();
    if (t < 32){
        int r = row0 + t;
        #pragma unroll
        for (int h = 0; h < 10; h++){
            float s = 0.f, dd = 0.f;
            #pragma unroll
            for (int c = 0; c < 10; c++){
                float v = Hl[t*100 + h*10 + c];
                s  += v*Al[h*10 + c];
                dd += v*Al[100 + h*10 + c];
            }
            as2[r*10 + h] = s;
            ad2[r*10 + h] = dd;
        }
    }
}

// ---------- agg layer2: one block (128 thr) per dst node, head-mean ----------
__global__ __launch_bounds__(128) void agg2_kernel(
    const int* __restrict__ offs, const int* __restrict__ csr_src,
    const float* __restrict__ as2, const float* __restrict__ ad2,
    const float* __restrict__ h2, const float* __restrict__ b2,
    float* __restrict__ emb2_out /* d_out + 1 + N*128 */)
{
    __shared__ float sval[100];
    int d = blockIdx.x;
    int j = threadIdx.x;
    int e0 = offs[d], e1 = offs[d+1];
    if (j < 100){
        int h = j/10;
        float ad = ad2[d*10 + h];
        float acc = 0.f, wsum = 0.f;
        for (int i = e0; i < e1; i++){
            int s = csr_src[i];
            float w = __expf(lrelu(as2[s*10 + h] + ad));
            acc += w*h2[(size_t)s*100 + j];
            wsum += w;
        }
        sval[j] = acc/(wsum + 1e-16f);
    }
    __syncthreads();
    if (j < 10){
        float s = 0.f;
        #pragma unroll
        for (int h = 0; h < 10; h++) s += sval[h*10 + j];
        emb2_out[(size_t)d*10 + j] = s*0.1f + b2[j];
    }
}

// ---------- loss ----------
__global__ __launch_bounds__(256) void loss_kernel(
    const float* __restrict__ emb2, const int* __restrict__ labels,
    const int* __restrict__ mask, float* __restrict__ acc)
{
    int i = blockIdx.x*256 + threadIdx.x;
    float num = 0.f, den = 0.f;
    if (i < N_NODES && mask[i] != 0){
        const float* v = emb2 + (size_t)i*10;
        float m = v[0];
        #pragma unroll
        for (int c = 1; c < 10; c++) m = fmaxf(m, v[c]);
        float s = 0.f;
        #pragma unroll
        for (int c = 0; c < 10; c++) s += __expf(v[c]-m);
        float lse = m + __logf(s);
        num = lse - v[labels[i]];
        den = 1.f;
    }
    #pragma unroll
    for (int o = 32; o >= 1; o >>= 1){ num += __shfl_down(num, o); den += __shfl_down(den, o); }
    if ((threadIdx.x & 63) == 0){
        atomicAdd(&acc[0], num);
        atomicAdd(&acc[1], den);
    }
}

__global__ void finalize_kernel(const float* __restrict__ acc, float* __restrict__ out0){
    out0[0] = acc[0]/acc[1];
}

extern "C" void kernel_launch(void* const* d_in, const int* in_sizes, int n_in,
                              void* d_out, int out_size, void* d_ws, size_t ws_size,
                              hipStream_t stream) {
    const float* x      = (const float*)d_in[0];
    const int*   ei     = (const int*)d_in[1];
    const int*   labels = (const int*)d_in[2];
    const int*   mask   = (const int*)d_in[3];
    const float* W1     = (const float*)d_in[4];
    const float* a_src1 = (const float*)d_in[5];
    const float* a_dst1 = (const float*)d_in[6];
    const float* b1     = (const float*)d_in[7];
    const float* W2     = (const float*)d_in[8];
    const float* a_src2 = (const float*)d_in[9];
    const float* a_dst2 = (const float*)d_in[10];
    const float* b2     = (const float*)d_in[11];

    float* out  = (float*)d_out;
    float* emb1 = out + 1;                       // [N,128]
    float* emb2 = out + 1 + (size_t)N_NODES*128; // [N,10]

    float* ws = (float*)d_ws;
    float* h1   = ws;                     // 12,800,000
    float* as1  = h1  + (size_t)N_NODES*128;
    float* ad1  = as1 + (size_t)N_NODES*8;
    float* h2   = ad1 + (size_t)N_NODES*8;   // 10,000,000
    float* as2  = h2  + (size_t)N_NODES*100;
    float* ad2  = as2 + (size_t)N_NODES*10;
    float* lacc = ad2 + (size_t)N_NODES*10;  // 4 floats
    int* counts = (int*)(lacc + 4);          // N
    int* offs   = counts + N_NODES;          // N+1
    int* cursor = offs + N_NODES + 1;        // N+1
    int* csr    = cursor + N_NODES + 1;      // E

    hipMemsetAsync(counts, 0, N_NODES*sizeof(int), stream);
    hipMemsetAsync(lacc, 0, 4*sizeof(float), stream);

    count_kernel<<<N_EDGES/256, 256, 0, stream>>>(ei, counts);
    scan_kernel<<<1, 1024, 0, stream>>>(counts, offs, cursor);
    scatter_kernel<<<N_EDGES/256, 256, 0, stream>>>(ei, cursor, csr);

    gemm1_kernel<<<N_NODES/32, 256, 0, stream>>>(x, W1, a_src1, a_dst1, h1, as1, ad1);
    agg1_kernel<<<N_NODES/4, 256, 0, stream>>>(offs, csr, as1, ad1, h1, b1, emb1);
    gemm2_kernel<<<N_NODES/32, 256, 0, stream>>>(emb1, W2, a_src2, a_dst2, h2, as2, ad2);
    agg2_kernel<<<N_NODES, 128, 0, stream>>>(offs, csr, as2, ad2, h2, b2, emb2);
    loss_kernel<<<(N_NODES+255)/256, 256, 0, stream>>>(emb2, labels, mask, lacc);
    finalize_kernel<<<1, 1, 0, stream>>>(lacc, out);
}

// Round 2
// 508.336 us; speedup vs baseline: 1.4236x; 1.4236x over previous
//
#include <hip/hip_runtime.h>
#include <hip/hip_bf16.h>
#include <math.h>

#define N_NODES 100000
#define N_EDGES 800000
#define NB_SCAN ((N_NODES + 1023) / 1024)   // 98

__device__ __forceinline__ float lrelu(float v){ return v > 0.f ? v : 0.2f*v; }
__device__ __forceinline__ float eluf(float v){ return v > 0.f ? v : (__expf(v) - 1.f); }

// ---------- CSR build ----------
__global__ __launch_bounds__(256) void count_kernel(const int* __restrict__ ei, int* __restrict__ counts){
    int e = blockIdx.x*256 + threadIdx.x;
    if (e < N_EDGES) atomicAdd(&counts[ei[N_EDGES + e]], 1);
}

// level-1: per-block exclusive scan of counts, emit block sums
__global__ __launch_bounds__(1024) void scan_blocks_kernel(const int* __restrict__ counts,
                                                           int* __restrict__ exoffs,
                                                           int* __restrict__ bsums){
    __shared__ int buf[1024];
    int t = threadIdx.x;
    int gid = blockIdx.x*1024 + t;
    int v = (gid < N_NODES) ? counts[gid] : 0;
    buf[t] = v;
    __syncthreads();
    #pragma unroll
    for (int off = 1; off < 1024; off <<= 1){
        int u = (t >= off) ? buf[t-off] : 0;
        __syncthreads();
        buf[t] += u;
        __syncthreads();
    }
    if (gid < N_NODES) exoffs[gid] = buf[t] - v;   // exclusive within block
    if (t == 1023) bsums[blockIdx.x] = buf[1023];
}

// level-2: scan the 98 block sums (tiny)
__global__ void scan_sums_kernel(const int* __restrict__ bsums, int* __restrict__ bpre){
    if (threadIdx.x == 0){
        int run = 0;
        #pragma unroll 4
        for (int b = 0; b < NB_SCAN; b++){ int v = bsums[b]; bpre[b] = run; run += v; }
    }
}

// level-3: add block prefix, write offs + cursor
__global__ __launch_bounds__(1024) void scan_add_kernel(const int* __restrict__ exoffs,
                                                        const int* __restrict__ bpre,
                                                        int* __restrict__ offs,
                                                        int* __restrict__ cursor){
    int gid = blockIdx.x*1024 + threadIdx.x;
    if (gid < N_NODES){
        int v = exoffs[gid] + bpre[blockIdx.x];
        offs[gid] = v;
        cursor[gid] = v;
    }
    if (gid == 0) offs[N_NODES] = N_EDGES;  // total edges is constant
}

__global__ __launch_bounds__(256) void scatter_kernel(const int* __restrict__ ei,
                                                      int* __restrict__ cursor, int* __restrict__ csr_src){
    int e = blockIdx.x*256 + threadIdx.x;
    if (e < N_EDGES){
        int d = ei[N_EDGES + e];
        int slot = atomicAdd(&cursor[d], 1);
        csr_src[slot] = ei[e];
    }
}

// ---------- GEMM1: h1 = x @ W1  (+ fused alpha_src1/alpha_dst1) ----------
__global__ __launch_bounds__(256) void gemm1_kernel(
    const float* __restrict__ x, const float* __restrict__ W1,
    const float* __restrict__ a_src, const float* __restrict__ a_dst,
    float* __restrict__ h1, float* __restrict__ as1, float* __restrict__ ad1)
{
    __shared__ float Wl[128*128];
    __shared__ float Xl[32*128];
    int t = threadIdx.x;
    const float4* W4 = (const float4*)W1;
    float4* Wl4 = (float4*)Wl;
    for (int i = t; i < 4096; i += 256) Wl4[i] = W4[i];
    int row0 = blockIdx.x*32;
    const float4* X4 = (const float4*)(x + (size_t)row0*128);
    float4* Xl4 = (float4*)Xl;
    for (int i = t; i < 1024; i += 256) Xl4[i] = X4[i];
    __syncthreads();

    int tx = t & 31, ty = t >> 5;
    int c0 = tx*4;
    int rbase = ty*4;
    float4 acc[4];
    #pragma unroll
    for (int r = 0; r < 4; r++) acc[r] = float4{0.f,0.f,0.f,0.f};

    for (int k = 0; k < 128; k += 4){
        float4 xr[4];
        #pragma unroll
        for (int ri = 0; ri < 4; ri++) xr[ri] = *(const float4*)&Xl[(rbase+ri)*128 + k];
        #pragma unroll
        for (int kk = 0; kk < 4; kk++){
            float4 w = *(const float4*)&Wl[(k+kk)*128 + c0];
            #pragma unroll
            for (int ri = 0; ri < 4; ri++){
                float xv = (kk==0)?xr[ri].x:(kk==1)?xr[ri].y:(kk==2)?xr[ri].z:xr[ri].w;
                acc[ri].x += xv*w.x; acc[ri].y += xv*w.y; acc[ri].z += xv*w.z; acc[ri].w += xv*w.w;
            }
        }
    }
    #pragma unroll
    for (int ri = 0; ri < 4; ri++){
        int r = row0 + rbase + ri;
        *(float4*)&h1[(size_t)r*128 + c0] = acc[ri];
    }
    // fused alpha projections: a_src/a_dst are [8][16] flat = 128 entries; col index == c0+j
    int head = tx >> 2;
    #pragma unroll
    for (int ri = 0; ri < 4; ri++){
        float ps = acc[ri].x*a_src[c0] + acc[ri].y*a_src[c0+1] + acc[ri].z*a_src[c0+2] + acc[ri].w*a_src[c0+3];
        float pd = acc[ri].x*a_dst[c0] + acc[ri].y*a_dst[c0+1] + acc[ri].z*a_dst[c0+2] + acc[ri].w*a_dst[c0+3];
        ps += __shfl_xor(ps, 1); ps += __shfl_xor(ps, 2);
        pd += __shfl_xor(pd, 1); pd += __shfl_xor(pd, 2);
        if ((tx & 3) == 0){
            int r = row0 + rbase + ri;
            as1[r*8 + head] = ps;
            ad1[r*8 + head] = pd;
        }
    }
}

// ---------- agg layer1: one wave per dst node ----------
__global__ __launch_bounds__(256) void agg1_kernel(
    const int* __restrict__ offs, const int* __restrict__ csr_src,
    const float* __restrict__ as1, const float* __restrict__ ad1,
    const float* __restrict__ h1, const float* __restrict__ b1,
    float* __restrict__ emb1_out /* d_out + 1 */)
{
    int wave = threadIdx.x >> 6;
    int lane = threadIdx.x & 63;
    int d = blockIdx.x*4 + wave;
    if (d >= N_NODES) return;
    int h = lane >> 3;                 // head 0..7
    int col = 2*lane;                  // = h*16 + (lane&7)*2
    int e0 = offs[d], e1 = offs[d+1];
    float ad = ad1[d*8 + h];
    float acc0 = 0.f, acc1 = 0.f, wsum = 0.f;
    for (int i = e0; i < e1; i++){
        int s = csr_src[i];
        float w = __expf(lrelu(as1[s*8 + h] + ad));
        const float* hp = h1 + (size_t)s*128 + col;
        acc0 += w*hp[0]; acc1 += w*hp[1];
        wsum += w;
    }
    float inv = 1.f/(wsum + 1e-16f);
    emb1_out[(size_t)d*128 + col]     = acc0*inv + b1[col];
    emb1_out[(size_t)d*128 + col + 1] = acc1*inv + b1[col+1];
}

// ---------- GEMM2: h2 = elu(emb1) @ W2 (+ fused alpha_src2/alpha_dst2) ----------
__global__ __launch_bounds__(256) void gemm2_kernel(
    const float* __restrict__ emb1g /* d_out+1 */, const float* __restrict__ W2,
    const float* __restrict__ a_src2, const float* __restrict__ a_dst2,
    float* __restrict__ h2, float* __restrict__ as2, float* __restrict__ ad2)
{
    __shared__ float Wl[128*100];
    __shared__ float Xl[32*128];
    __shared__ float Hl[32*100];
    __shared__ float Al[200];
    int t = threadIdx.x;
    const float4* W4 = (const float4*)W2;
    float4* Wl4 = (float4*)Wl;
    for (int i = t; i < 3200; i += 256) Wl4[i] = W4[i];
    int row0 = blockIdx.x*32;
    for (int i = t; i < 4096; i += 256) Xl[i] = eluf(emb1g[(size_t)row0*128 + i]);
    if (t < 200) Al[t] = (t < 100) ? a_src2[t] : a_dst2[t-100];
    __syncthreads();

    int tx = t & 31, ty = t >> 5;
    int c0 = tx*4;
    bool active = (c0 < 100);
    int rbase = ty*4;
    float4 acc[4];
    #pragma unroll
    for (int r = 0; r < 4; r++) acc[r] = float4{0.f,0.f,0.f,0.f};

    if (active){
        for (int k = 0; k < 128; k += 4){
            float4 xr[4];
            #pragma unroll
            for (int ri = 0; ri < 4; ri++) xr[ri] = *(const float4*)&Xl[(rbase+ri)*128 + k];
            #pragma unroll
            for (int kk = 0; kk < 4; kk++){
                float4 w = *(const float4*)&Wl[(k+kk)*100 + c0];
                #pragma unroll
                for (int ri = 0; ri < 4; ri++){
                    float xv = (kk==0)?xr[ri].x:(kk==1)?xr[ri].y:(kk==2)?xr[ri].z:xr[ri].w;
                    acc[ri].x += xv*w.x; acc[ri].y += xv*w.y; acc[ri].z += xv*w.z; acc[ri].w += xv*w.w;
                }
            }
        }
        #pragma unroll
        for (int ri = 0; ri < 4; ri++){
            int r = row0 + rbase + ri;
            *(float4*)&h2[(size_t)r*100 + c0] = acc[ri];
            *(float4*)&Hl[(rbase+ri)*100 + c0] = acc[ri];
        }
    }
    __syncthreads();
    if (t < 32){
        int r = row0 + t;
        #pragma unroll
        for (int h = 0; h < 10; h++){
            float s = 0.f, dd = 0.f;
            #pragma unroll
            for (int c = 0; c < 10; c++){
                float v = Hl[t*100 + h*10 + c];
                s  += v*Al[h*10 + c];
                dd += v*Al[100 + h*10 + c];
            }
            as2[r*10 + h] = s;
            ad2[r*10 + h] = dd;
        }
    }
}

// ---------- agg layer2: one block (128 thr) per dst node, head-mean ----------
__global__ __launch_bounds__(128) void agg2_kernel(
    const int* __restrict__ offs, const int* __restrict__ csr_src,
    const float* __restrict__ as2, const float* __restrict__ ad2,
    const float* __restrict__ h2, const float* __restrict__ b2,
    float* __restrict__ emb2_out /* d_out + 1 + N*128 */)
{
    __shared__ float sval[100];
    int d = blockIdx.x;
    int j = threadIdx.x;
    int e0 = offs[d], e1 = offs[d+1];
    if (j < 100){
        int h = j/10;
        float ad = ad2[d*10 + h];
        float acc = 0.f, wsum = 0.f;
        for (int i = e0; i < e1; i++){
            int s = csr_src[i];
            float w = __expf(lrelu(as2[s*10 + h] + ad));
            acc += w*h2[(size_t)s*100 + j];
            wsum += w;
        }
        sval[j] = acc/(wsum + 1e-16f);
    }
    __syncthreads();
    if (j < 10){
        float s = 0.f;
        #pragma unroll
        for (int h = 0; h < 10; h++) s += sval[h*10 + j];
        emb2_out[(size_t)d*10 + j] = s*0.1f + b2[j];
    }
}

// ---------- loss ----------
__global__ __launch_bounds__(256) void loss_kernel(
    const float* __restrict__ emb2, const int* __restrict__ labels,
    const int* __restrict__ mask, float* __restrict__ acc)
{
    int i = blockIdx.x*256 + threadIdx.x;
    float num = 0.f, den = 0.f;
    if (i < N_NODES && mask[i] != 0){
        const float* v = emb2 + (size_t)i*10;
        float m = v[0];
        #pragma unroll
        for (int c = 1; c < 10; c++) m = fmaxf(m, v[c]);
        float s = 0.f;
        #pragma unroll
        for (int c = 0; c < 10; c++) s += __expf(v[c]-m);
        float lse = m + __logf(s);
        num = lse - v[labels[i]];
        den = 1.f;
    }
    #pragma unroll
    for (int o = 32; o >= 1; o >>= 1){ num += __shfl_down(num, o); den += __shfl_down(den, o); }
    if ((threadIdx.x & 63) == 0){
        atomicAdd(&acc[0], num);
        atomicAdd(&acc[1], den);
    }
}

__global__ void finalize_kernel(const float* __restrict__ acc, float* __restrict__ out0){
    out0[0] = acc[0]/acc[1];
}

extern "C" void kernel_launch(void* const* d_in, const int* in_sizes, int n_in,
                              void* d_out, int out_size, void* d_ws, size_t ws_size,
                              hipStream_t stream) {
    const float* x      = (const float*)d_in[0];
    const int*   ei     = (const int*)d_in[1];
    const int*   labels = (const int*)d_in[2];
    const int*   mask   = (const int*)d_in[3];
    const float* W1     = (const float*)d_in[4];
    const float* a_src1 = (const float*)d_in[5];
    const float* a_dst1 = (const float*)d_in[6];
    const float* b1     = (const float*)d_in[7];
    const float* W2     = (const float*)d_in[8];
    const float* a_src2 = (const float*)d_in[9];
    const float* a_dst2 = (const float*)d_in[10];
    const float* b2     = (const float*)d_in[11];

    float* out  = (float*)d_out;
    float* emb1 = out + 1;                       // [N,128]
    float* emb2 = out + 1 + (size_t)N_NODES*128; // [N,10]

    float* ws = (float*)d_ws;
    float* h1   = ws;                     // N*128
    float* as1  = h1  + (size_t)N_NODES*128;
    float* ad1  = as1 + (size_t)N_NODES*8;
    float* h2   = ad1 + (size_t)N_NODES*8;   // N*100
    float* as2  = h2  + (size_t)N_NODES*100;
    float* ad2  = as2 + (size_t)N_NODES*10;
    float* lacc = ad2 + (size_t)N_NODES*10;  // 4 floats
    int* counts = (int*)(lacc + 4);          // N
    int* offs   = counts + N_NODES;          // N+1
    int* cursor = offs + N_NODES + 1;        // N+1
    int* csr    = cursor + N_NODES + 1;      // E
    int* exoffs = csr + N_EDGES;             // N
    int* bsums  = exoffs + N_NODES;          // NB_SCAN
    int* bpre   = bsums + NB_SCAN;           // NB_SCAN

    hipMemsetAsync(counts, 0, N_NODES*sizeof(int), stream);
    hipMemsetAsync(lacc, 0, 4*sizeof(float), stream);

    count_kernel<<<N_EDGES/256, 256, 0, stream>>>(ei, counts);
    scan_blocks_kernel<<<NB_SCAN, 1024, 0, stream>>>(counts, exoffs, bsums);
    scan_sums_kernel<<<1, 64, 0, stream>>>(bsums, bpre);
    scan_add_kernel<<<NB_SCAN, 1024, 0, stream>>>(exoffs, bpre, offs, cursor);
    scatter_kernel<<<N_EDGES/256, 256, 0, stream>>>(ei, cursor, csr);

    gemm1_kernel<<<N_NODES/32, 256, 0, stream>>>(x, W1, a_src1, a_dst1, h1, as1, ad1);
    agg1_kernel<<<N_NODES/4, 256, 0, stream>>>(offs, csr, as1, ad1, h1, b1, emb1);
    gemm2_kernel<<<N_NODES/32, 256, 0, stream>>>(emb1, W2, a_src2, a_dst2, h2, as2, ad2);
    agg2_kernel<<<N_NODES, 128, 0, stream>>>(offs, csr, as2, ad2, h2, b2, emb2);
    loss_kernel<<<(N_NODES+255)/256, 256, 0, stream>>>(emb2, labels, mask, lacc);
    finalize_kernel<<<1, 1, 0, stream>>>(lacc, out);
}

// Round 3
// 431.390 us; speedup vs baseline: 1.6775x; 1.1784x over previous
//
#include <hip/hip_runtime.h>
#include <hip/hip_bf16.h>
#include <math.h>

#define N_NODES 100000
#define N_EDGES 800000
#define NB_SCAN ((N_NODES + 1023) / 1024)   // 98

__device__ __forceinline__ float lrelu(float v){ return v > 0.f ? v : 0.2f*v; }
__device__ __forceinline__ float eluf(float v){ return v > 0.f ? v : (__expf(v) - 1.f); }

__device__ __forceinline__ unsigned short f2bf(float f){
    union { float f; unsigned u; } v; v.f = f;
    unsigned r = (v.u + 0x7fff + ((v.u >> 16) & 1)) >> 16;
    return (unsigned short)r;
}
__device__ __forceinline__ float bf2f(unsigned short u){
    union { unsigned u; float f; } v; v.u = ((unsigned)u) << 16;
    return v.f;
}

// ---------- CSR build ----------
__global__ __launch_bounds__(256) void count_kernel(const int* __restrict__ ei, int* __restrict__ counts){
    int e = blockIdx.x*256 + threadIdx.x;
    if (e < N_EDGES) atomicAdd(&counts[ei[N_EDGES + e]], 1);
}

__global__ __launch_bounds__(1024) void scan_blocks_kernel(const int* __restrict__ counts,
                                                           int* __restrict__ exoffs,
                                                           int* __restrict__ bsums){
    __shared__ int buf[1024];
    int t = threadIdx.x;
    int gid = blockIdx.x*1024 + t;
    int v = (gid < N_NODES) ? counts[gid] : 0;
    buf[t] = v;
    __syncthreads();
    #pragma unroll
    for (int off = 1; off < 1024; off <<= 1){
        int u = (t >= off) ? buf[t-off] : 0;
        __syncthreads();
        buf[t] += u;
        __syncthreads();
    }
    if (gid < N_NODES) exoffs[gid] = buf[t] - v;
    if (t == 1023) bsums[blockIdx.x] = buf[1023];
}

__global__ void scan_sums_kernel(const int* __restrict__ bsums, int* __restrict__ bpre){
    if (threadIdx.x == 0){
        int run = 0;
        #pragma unroll 4
        for (int b = 0; b < NB_SCAN; b++){ int v = bsums[b]; bpre[b] = run; run += v; }
    }
}

__global__ __launch_bounds__(1024) void scan_add_kernel(const int* __restrict__ exoffs,
                                                        const int* __restrict__ bpre,
                                                        int* __restrict__ offs,
                                                        int* __restrict__ cursor){
    int gid = blockIdx.x*1024 + threadIdx.x;
    if (gid < N_NODES){
        int v = exoffs[gid] + bpre[blockIdx.x];
        offs[gid] = v;
        cursor[gid] = v;
    }
    if (gid == 0) offs[N_NODES] = N_EDGES;
}

__global__ __launch_bounds__(256) void scatter_kernel(const int* __restrict__ ei,
                                                      int* __restrict__ cursor, int* __restrict__ csr_src){
    int e = blockIdx.x*256 + threadIdx.x;
    if (e < N_EDGES){
        int d = ei[N_EDGES + e];
        int slot = atomicAdd(&cursor[d], 1);
        csr_src[slot] = ei[e];
    }
}

// ---------- GEMM1: h1 = x @ W1, stored bf16 (+ fused alpha projections f32) ----------
__global__ __launch_bounds__(256) void gemm1_kernel(
    const float* __restrict__ x, const float* __restrict__ W1,
    const float* __restrict__ a_src, const float* __restrict__ a_dst,
    unsigned short* __restrict__ h1bf, float* __restrict__ as1, float* __restrict__ ad1)
{
    __shared__ float Wl[128*128];
    __shared__ float Xl[32*128];
    int t = threadIdx.x;
    const float4* W4 = (const float4*)W1;
    float4* Wl4 = (float4*)Wl;
    for (int i = t; i < 4096; i += 256) Wl4[i] = W4[i];
    int row0 = blockIdx.x*32;
    const float4* X4 = (const float4*)(x + (size_t)row0*128);
    float4* Xl4 = (float4*)Xl;
    for (int i = t; i < 1024; i += 256) Xl4[i] = X4[i];
    __syncthreads();

    int tx = t & 31, ty = t >> 5;
    int c0 = tx*4;
    int rbase = ty*4;
    float4 acc[4];
    #pragma unroll
    for (int r = 0; r < 4; r++) acc[r] = float4{0.f,0.f,0.f,0.f};

    for (int k = 0; k < 128; k += 4){
        float4 xr[4];
        #pragma unroll
        for (int ri = 0; ri < 4; ri++) xr[ri] = *(const float4*)&Xl[(rbase+ri)*128 + k];
        #pragma unroll
        for (int kk = 0; kk < 4; kk++){
            float4 w = *(const float4*)&Wl[(k+kk)*128 + c0];
            #pragma unroll
            for (int ri = 0; ri < 4; ri++){
                float xv = (kk==0)?xr[ri].x:(kk==1)?xr[ri].y:(kk==2)?xr[ri].z:xr[ri].w;
                acc[ri].x += xv*w.x; acc[ri].y += xv*w.y; acc[ri].z += xv*w.z; acc[ri].w += xv*w.w;
            }
        }
    }
    #pragma unroll
    for (int ri = 0; ri < 4; ri++){
        int r = row0 + rbase + ri;
        ushort4 o;
        o.x = f2bf(acc[ri].x); o.y = f2bf(acc[ri].y);
        o.z = f2bf(acc[ri].z); o.w = f2bf(acc[ri].w);
        *(ushort4*)&h1bf[(size_t)r*128 + c0] = o;
    }
    int head = tx >> 2;
    #pragma unroll
    for (int ri = 0; ri < 4; ri++){
        float ps = acc[ri].x*a_src[c0] + acc[ri].y*a_src[c0+1] + acc[ri].z*a_src[c0+2] + acc[ri].w*a_src[c0+3];
        float pd = acc[ri].x*a_dst[c0] + acc[ri].y*a_dst[c0+1] + acc[ri].z*a_dst[c0+2] + acc[ri].w*a_dst[c0+3];
        ps += __shfl_xor(ps, 1); ps += __shfl_xor(ps, 2);
        pd += __shfl_xor(pd, 1); pd += __shfl_xor(pd, 2);
        if ((tx & 3) == 0){
            int r = row0 + rbase + ri;
            as1[r*8 + head] = ps;
            ad1[r*8 + head] = pd;
        }
    }
}

// ---------- agg layer1: one wave per dst; shfl-broadcast edge indices ----------
__global__ __launch_bounds__(256) void agg1_kernel(
    const int* __restrict__ offs, const int* __restrict__ csr_src,
    const float* __restrict__ as1, const float* __restrict__ ad1,
    const unsigned short* __restrict__ h1bf, const float* __restrict__ b1,
    float* __restrict__ emb1_out /* d_out + 1 */)
{
    int wave = threadIdx.x >> 6;
    int lane = threadIdx.x & 63;
    int d = blockIdx.x*4 + wave;
    if (d >= N_NODES) return;
    int h = lane >> 3;
    int col = 2*lane;
    int e0 = offs[d], e1 = offs[d+1];
    float ad = ad1[d*8 + h];
    float acc0 = 0.f, acc1 = 0.f, wsum = 0.f;

    for (int base = e0; base < e1; base += 64){
        int ii = base + lane;
        int sv = (ii < e1) ? csr_src[ii] : 0;
        int n = min(64, e1 - base);
        int i = 0;
        for (; i + 1 < n; i += 2){
            int s0 = __shfl(sv, i);
            int s1 = __shfl(sv, i+1);
            float l0 = as1[s0*8 + h];
            float l1 = as1[s1*8 + h];
            unsigned hv0 = *(const unsigned*)(h1bf + (size_t)s0*128 + col);
            unsigned hv1 = *(const unsigned*)(h1bf + (size_t)s1*128 + col);
            float w0 = __expf(lrelu(l0 + ad));
            float w1 = __expf(lrelu(l1 + ad));
            acc0 += w0*bf2f((unsigned short)hv0) + w1*bf2f((unsigned short)hv1);
            acc1 += w0*bf2f((unsigned short)(hv0>>16)) + w1*bf2f((unsigned short)(hv1>>16));
            wsum += w0 + w1;
        }
        if (i < n){
            int s0 = __shfl(sv, i);
            float w0 = __expf(lrelu(as1[s0*8 + h] + ad));
            unsigned hv0 = *(const unsigned*)(h1bf + (size_t)s0*128 + col);
            acc0 += w0*bf2f((unsigned short)hv0);
            acc1 += w0*bf2f((unsigned short)(hv0>>16));
            wsum += w0;
        }
    }
    float inv = 1.f/(wsum + 1e-16f);
    emb1_out[(size_t)d*128 + col]     = acc0*inv + b1[col];
    emb1_out[(size_t)d*128 + col + 1] = acc1*inv + b1[col+1];
}

// ---------- GEMM2: h2 = elu(emb1) @ W2, stored bf16 (+ fused alpha projections) ----------
__global__ __launch_bounds__(256) void gemm2_kernel(
    const float* __restrict__ emb1g /* d_out+1 */, const float* __restrict__ W2,
    const float* __restrict__ a_src2, const float* __restrict__ a_dst2,
    unsigned short* __restrict__ h2bf, float* __restrict__ as2, float* __restrict__ ad2)
{
    __shared__ float Wl[128*100];
    __shared__ float Xl[32*128];
    __shared__ float Hl[32*100];
    __shared__ float Al[200];
    int t = threadIdx.x;
    const float4* W4 = (const float4*)W2;
    float4* Wl4 = (float4*)Wl;
    for (int i = t; i < 3200; i += 256) Wl4[i] = W4[i];
    int row0 = blockIdx.x*32;
    for (int i = t; i < 4096; i += 256) Xl[i] = eluf(emb1g[(size_t)row0*128 + i]);
    if (t < 200) Al[t] = (t < 100) ? a_src2[t] : a_dst2[t-100];
    __syncthreads();

    int tx = t & 31, ty = t >> 5;
    int c0 = tx*4;
    bool active = (c0 < 100);
    int rbase = ty*4;
    float4 acc[4];
    #pragma unroll
    for (int r = 0; r < 4; r++) acc[r] = float4{0.f,0.f,0.f,0.f};

    if (active){
        for (int k = 0; k < 128; k += 4){
            float4 xr[4];
            #pragma unroll
            for (int ri = 0; ri < 4; ri++) xr[ri] = *(const float4*)&Xl[(rbase+ri)*128 + k];
            #pragma unroll
            for (int kk = 0; kk < 4; kk++){
                float4 w = *(const float4*)&Wl[(k+kk)*100 + c0];
                #pragma unroll
                for (int ri = 0; ri < 4; ri++){
                    float xv = (kk==0)?xr[ri].x:(kk==1)?xr[ri].y:(kk==2)?xr[ri].z:xr[ri].w;
                    acc[ri].x += xv*w.x; acc[ri].y += xv*w.y; acc[ri].z += xv*w.z; acc[ri].w += xv*w.w;
                }
            }
        }
        #pragma unroll
        for (int ri = 0; ri < 4; ri++){
            int r = row0 + rbase + ri;
            ushort4 o;
            o.x = f2bf(acc[ri].x); o.y = f2bf(acc[ri].y);
            o.z = f2bf(acc[ri].z); o.w = f2bf(acc[ri].w);
            *(ushort4*)&h2bf[(size_t)r*100 + c0] = o;
            *(float4*)&Hl[(rbase+ri)*100 + c0] = acc[ri];
        }
    }
    __syncthreads();
    if (t < 32){
        int r = row0 + t;
        #pragma unroll
        for (int h = 0; h < 10; h++){
            float s = 0.f, dd = 0.f;
            #pragma unroll
            for (int c = 0; c < 10; c++){
                float v = Hl[t*100 + h*10 + c];
                s  += v*Al[h*10 + c];
                dd += v*Al[100 + h*10 + c];
            }
            as2[r*10 + h] = s;
            ad2[r*10 + h] = dd;
        }
    }
}

// ---------- agg layer2: one block (128 thr) per dst; LDS-staged edge indices ----------
__global__ __launch_bounds__(128) void agg2_kernel(
    const int* __restrict__ offs, const int* __restrict__ csr_src,
    const float* __restrict__ as2, const float* __restrict__ ad2,
    const unsigned short* __restrict__ h2bf, const float* __restrict__ b2,
    float* __restrict__ emb2_out)
{
    __shared__ float sval[100];
    __shared__ int sidx[128];
    int d = blockIdx.x;
    int t = threadIdx.x;
    int j = t;
    int e0 = offs[d], e1 = offs[d+1];
    int h = j/10;
    float ad = (j < 100) ? ad2[d*10 + h] : 0.f;
    float acc = 0.f, wsum = 0.f;

    for (int base = e0; base < e1; base += 128){
        int ii = base + t;
        if (ii < e1) sidx[t] = csr_src[ii];
        __syncthreads();
        int n = min(128, e1 - base);
        if (j < 100){
            int i = 0;
            for (; i + 1 < n; i += 2){
                int s0 = sidx[i], s1 = sidx[i+1];
                float l0 = as2[s0*10 + h];
                float l1 = as2[s1*10 + h];
                unsigned short v0 = h2bf[(size_t)s0*100 + j];
                unsigned short v1 = h2bf[(size_t)s1*100 + j];
                float w0 = __expf(lrelu(l0 + ad));
                float w1 = __expf(lrelu(l1 + ad));
                acc += w0*bf2f(v0) + w1*bf2f(v1);
                wsum += w0 + w1;
            }
            if (i < n){
                int s0 = sidx[i];
                float w0 = __expf(lrelu(as2[s0*10 + h] + ad));
                acc += w0*bf2f(h2bf[(size_t)s0*100 + j]);
                wsum += w0;
            }
        }
        __syncthreads();
    }
    if (j < 100) sval[j] = acc/(wsum + 1e-16f);
    __syncthreads();
    if (j < 10){
        float s = 0.f;
        #pragma unroll
        for (int hh = 0; hh < 10; hh++) s += sval[hh*10 + j];
        emb2_out[(size_t)d*10 + j] = s*0.1f + b2[j];
    }
}

// ---------- loss ----------
__global__ __launch_bounds__(256) void loss_kernel(
    const float* __restrict__ emb2, const int* __restrict__ labels,
    const int* __restrict__ mask, float* __restrict__ acc)
{
    int i = blockIdx.x*256 + threadIdx.x;
    float num = 0.f, den = 0.f;
    if (i < N_NODES && mask[i] != 0){
        const float* v = emb2 + (size_t)i*10;
        float m = v[0];
        #pragma unroll
        for (int c = 1; c < 10; c++) m = fmaxf(m, v[c]);
        float s = 0.f;
        #pragma unroll
        for (int c = 0; c < 10; c++) s += __expf(v[c]-m);
        float lse = m + __logf(s);
        num = lse - v[labels[i]];
        den = 1.f;
    }
    #pragma unroll
    for (int o = 32; o >= 1; o >>= 1){ num += __shfl_down(num, o); den += __shfl_down(den, o); }
    if ((threadIdx.x & 63) == 0){
        atomicAdd(&acc[0], num);
        atomicAdd(&acc[1], den);
    }
}

__global__ void finalize_kernel(const float* __restrict__ acc, float* __restrict__ out0){
    out0[0] = acc[0]/acc[1];
}

extern "C" void kernel_launch(void* const* d_in, const int* in_sizes, int n_in,
                              void* d_out, int out_size, void* d_ws, size_t ws_size,
                              hipStream_t stream) {
    const float* x      = (const float*)d_in[0];
    const int*   ei     = (const int*)d_in[1];
    const int*   labels = (const int*)d_in[2];
    const int*   mask   = (const int*)d_in[3];
    const float* W1     = (const float*)d_in[4];
    const float* a_src1 = (const float*)d_in[5];
    const float* a_dst1 = (const float*)d_in[6];
    const float* b1     = (const float*)d_in[7];
    const float* W2     = (const float*)d_in[8];
    const float* a_src2 = (const float*)d_in[9];
    const float* a_dst2 = (const float*)d_in[10];
    const float* b2     = (const float*)d_in[11];

    float* out  = (float*)d_out;
    float* emb1 = out + 1;                       // [N,128]
    float* emb2 = out + 1 + (size_t)N_NODES*128; // [N,10]

    unsigned short* h1bf = (unsigned short*)d_ws;              // N*128 bf16
    unsigned short* h2bf = h1bf + (size_t)N_NODES*128;         // N*100 bf16
    float* as1  = (float*)(h2bf + (size_t)N_NODES*100);
    float* ad1  = as1 + (size_t)N_NODES*8;
    float* as2  = ad1 + (size_t)N_NODES*8;
    float* ad2  = as2 + (size_t)N_NODES*10;
    float* lacc = ad2 + (size_t)N_NODES*10;  // 4 floats
    int* counts = (int*)(lacc + 4);          // N
    int* offs   = counts + N_NODES;          // N+1
    int* cursor = offs + N_NODES + 1;        // N+1
    int* csr    = cursor + N_NODES + 1;      // E
    int* exoffs = csr + N_EDGES;             // N
    int* bsums  = exoffs + N_NODES;          // NB_SCAN
    int* bpre   = bsums + NB_SCAN;           // NB_SCAN

    hipMemsetAsync(counts, 0, N_NODES*sizeof(int), stream);
    hipMemsetAsync(lacc, 0, 4*sizeof(float), stream);

    count_kernel<<<N_EDGES/256, 256, 0, stream>>>(ei, counts);
    scan_blocks_kernel<<<NB_SCAN, 1024, 0, stream>>>(counts, exoffs, bsums);
    scan_sums_kernel<<<1, 64, 0, stream>>>(bsums, bpre);
    scan_add_kernel<<<NB_SCAN, 1024, 0, stream>>>(exoffs, bpre, offs, cursor);
    scatter_kernel<<<N_EDGES/256, 256, 0, stream>>>(ei, cursor, csr);

    gemm1_kernel<<<N_NODES/32, 256, 0, stream>>>(x, W1, a_src1, a_dst1, h1bf, as1, ad1);
    agg1_kernel<<<N_NODES/4, 256, 0, stream>>>(offs, csr, as1, ad1, h1bf, b1, emb1);
    gemm2_kernel<<<N_NODES/32, 256, 0, stream>>>(emb1, W2, a_src2, a_dst2, h2bf, as2, ad2);
    agg2_kernel<<<N_NODES, 128, 0, stream>>>(offs, csr, as2, ad2, h2bf, b2, emb2);
    loss_kernel<<<(N_NODES+255)/256, 256, 0, stream>>>(emb2, labels, mask, lacc);
    finalize_kernel<<<1, 1, 0, stream>>>(lacc, out);
}

// Round 4
// 363.224 us; speedup vs baseline: 1.9923x; 1.1877x over previous
//
#include <hip/hip_runtime.h>
#include <hip/hip_bf16.h>
#include <math.h>

#define N_NODES 100000
#define N_EDGES 800000
#define NB_SCAN ((N_NODES + 1023) / 1024)   // 98

typedef __bf16 bf16x8 __attribute__((ext_vector_type(8)));
typedef float  f32x4  __attribute__((ext_vector_type(4)));

__device__ __forceinline__ float lrelu(float v){ return v > 0.f ? v : 0.2f*v; }
__device__ __forceinline__ float eluf(float v){ return v > 0.f ? v : (__expf(v) - 1.f); }

__device__ __forceinline__ unsigned short f2bf(float f){
    union { float f; unsigned u; } v; v.f = f;
    unsigned r = (v.u + 0x7fff + ((v.u >> 16) & 1)) >> 16;
    return (unsigned short)r;
}
__device__ __forceinline__ float bf2f(unsigned short u){
    union { unsigned u; float f; } v; v.u = ((unsigned)u) << 16;
    return v.f;
}

// ---------- CSR build ----------
__global__ __launch_bounds__(256) void count_kernel(const int* __restrict__ ei, int* __restrict__ counts){
    int e = blockIdx.x*256 + threadIdx.x;
    if (e < N_EDGES) atomicAdd(&counts[ei[N_EDGES + e]], 1);
}

__global__ __launch_bounds__(1024) void scan_blocks_kernel(const int* __restrict__ counts,
                                                           int* __restrict__ exoffs,
                                                           int* __restrict__ bsums){
    __shared__ int buf[1024];
    int t = threadIdx.x;
    int gid = blockIdx.x*1024 + t;
    int v = (gid < N_NODES) ? counts[gid] : 0;
    buf[t] = v;
    __syncthreads();
    #pragma unroll
    for (int off = 1; off < 1024; off <<= 1){
        int u = (t >= off) ? buf[t-off] : 0;
        __syncthreads();
        buf[t] += u;
        __syncthreads();
    }
    if (gid < N_NODES) exoffs[gid] = buf[t] - v;
    if (t == 1023) bsums[blockIdx.x] = buf[1023];
}

__global__ void scan_sums_kernel(const int* __restrict__ bsums, int* __restrict__ bpre){
    if (threadIdx.x == 0){
        int run = 0;
        #pragma unroll 4
        for (int b = 0; b < NB_SCAN; b++){ int v = bsums[b]; bpre[b] = run; run += v; }
    }
}

__global__ __launch_bounds__(1024) void scan_add_kernel(const int* __restrict__ exoffs,
                                                        const int* __restrict__ bpre,
                                                        int* __restrict__ offs,
                                                        int* __restrict__ cursor){
    int gid = blockIdx.x*1024 + threadIdx.x;
    if (gid < N_NODES){
        int v = exoffs[gid] + bpre[blockIdx.x];
        offs[gid] = v;
        cursor[gid] = v;
    }
    if (gid == 0) offs[N_NODES] = N_EDGES;
}

__global__ __launch_bounds__(256) void scatter_kernel(const int* __restrict__ ei,
                                                      int* __restrict__ cursor, int* __restrict__ csr_src){
    int e = blockIdx.x*256 + threadIdx.x;
    if (e < N_EDGES){
        int d = ei[N_EDGES + e];
        int slot = atomicAdd(&cursor[d], 1);
        csr_src[slot] = ei[e];
    }
}

// ---------- weight prep: transpose + bf16 ----------
__global__ __launch_bounds__(256) void prep_w1(const float* __restrict__ W1, unsigned short* __restrict__ wt1){
    int i = blockIdx.x*256 + threadIdx.x;
    if (i < 128*128){
        int n = i >> 7, k = i & 127;
        wt1[i] = f2bf(W1[k*128 + n]);
    }
}
__global__ __launch_bounds__(256) void prep_w2(const float* __restrict__ W2, unsigned short* __restrict__ wt2){
    int i = blockIdx.x*256 + threadIdx.x;
    if (i < 112*128){
        int n = i >> 7, k = i & 127;
        wt2[i] = (n < 100) ? f2bf(W2[k*100 + n]) : (unsigned short)0;
    }
}

// ---------- GEMM1 (MFMA): h1 = bf16(x) @ bf16(W1), epilogue fuses alpha1 ----------
__global__ __launch_bounds__(256) void gemm1_mfma(
    const float* __restrict__ x, const unsigned short* __restrict__ wt1,
    const float* __restrict__ a_src, const float* __restrict__ a_dst,
    unsigned short* __restrict__ h1bf, float* __restrict__ as1, float* __restrict__ ad1)
{
    __shared__ unsigned short Al[64*128];   // 16 KB, XOR-swizzled
    __shared__ unsigned short Bl[128*128];  // 32 KB, XOR-swizzled (rows = n of W^T)
    int t = threadIdx.x;
    int row0 = blockIdx.x*64;

    // stage A: 64 rows x 128 k, f32 -> bf16
    #pragma unroll
    for (int i = 0; i < 4; i++){
        int idx = (i*256 + t)*8;
        int r = idx >> 7, c = idx & 127;
        int grow = row0 + r;
        bf16x8 v;
        if (grow < N_NODES){
            const float4* p = (const float4*)(x + (size_t)grow*128 + c);
            float4 f0 = p[0], f1 = p[1];
            v[0]=(__bf16)f0.x; v[1]=(__bf16)f0.y; v[2]=(__bf16)f0.z; v[3]=(__bf16)f0.w;
            v[4]=(__bf16)f1.x; v[5]=(__bf16)f1.y; v[6]=(__bf16)f1.z; v[7]=(__bf16)f1.w;
        } else {
            #pragma unroll
            for (int j = 0; j < 8; j++) v[j] = (__bf16)0.f;
        }
        int byte = (r*256 + c*2) ^ ((r&7)<<4);
        *(bf16x8*)((char*)Al + byte) = v;
    }
    // stage B: wt1 [128][128] bf16 row-major (row=n, col=k)
    #pragma unroll
    for (int i = 0; i < 8; i++){
        int idx = (i*256 + t)*8;
        int n = idx >> 7, c = idx & 127;
        bf16x8 v = *(const bf16x8*)(wt1 + n*128 + c);
        int byte = (n*256 + c*2) ^ ((n&7)<<4);
        *(bf16x8*)((char*)Bl + byte) = v;
    }
    __syncthreads();

    int wv = t >> 6, l = t & 63;
    int lr = l & 15, lg = l >> 4;
    bf16x8 af[4];
    #pragma unroll
    for (int ks = 0; ks < 4; ks++){
        int r = wv*16 + lr;
        int byte = (r*256 + (ks*32 + lg*8)*2) ^ ((r&7)<<4);
        af[ks] = *(const bf16x8*)((const char*)Al + byte);
    }
    f32x4 acc[8];
    #pragma unroll
    for (int nt = 0; nt < 8; nt++){
        acc[nt] = (f32x4){0.f,0.f,0.f,0.f};
        #pragma unroll
        for (int ks = 0; ks < 4; ks++){
            int n = nt*16 + lr;
            int byte = (n*256 + (ks*32 + lg*8)*2) ^ ((n&7)<<4);
            bf16x8 bfv = *(const bf16x8*)((const char*)Bl + byte);
            acc[nt] = __builtin_amdgcn_mfma_f32_16x16x32_bf16(af[ks], bfv, acc[nt], 0, 0, 0);
        }
    }
    // epilogue: C/D layout col=lane&15, row=(lane>>4)*4+reg  [m89]
    int orow_base = row0 + wv*16 + lg*4;
    #pragma unroll
    for (int nt = 0; nt < 8; nt++){
        float avs = a_src[nt*16 + lr];
        float avd = a_dst[nt*16 + lr];
        #pragma unroll
        for (int r = 0; r < 4; r++){
            int grow = orow_base + r;
            float v = acc[nt][r];
            if (grow < N_NODES) h1bf[(size_t)grow*128 + nt*16 + lr] = f2bf(v);
            float ps = v*avs, pd = v*avd;
            ps += __shfl_xor(ps,1); ps += __shfl_xor(ps,2); ps += __shfl_xor(ps,4); ps += __shfl_xor(ps,8);
            pd += __shfl_xor(pd,1); pd += __shfl_xor(pd,2); pd += __shfl_xor(pd,4); pd += __shfl_xor(pd,8);
            if (lr == 0 && grow < N_NODES){
                as1[grow*8 + nt] = ps;
                ad1[grow*8 + nt] = pd;
            }
        }
    }
}

// ---------- agg layer1 ----------
__global__ __launch_bounds__(256) void agg1_kernel(
    const int* __restrict__ offs, const int* __restrict__ csr_src,
    const float* __restrict__ as1, const float* __restrict__ ad1,
    const unsigned short* __restrict__ h1bf, const float* __restrict__ b1,
    float* __restrict__ emb1_out /* d_out + 1 */)
{
    int wave = threadIdx.x >> 6;
    int lane = threadIdx.x & 63;
    int d = blockIdx.x*4 + wave;
    if (d >= N_NODES) return;
    int h = lane >> 3;
    int col = 2*lane;
    int e0 = offs[d], e1 = offs[d+1];
    float ad = ad1[d*8 + h];
    float acc0 = 0.f, acc1 = 0.f, wsum = 0.f;

    for (int base = e0; base < e1; base += 64){
        int ii = base + lane;
        int sv = (ii < e1) ? csr_src[ii] : 0;
        int n = min(64, e1 - base);
        int i = 0;
        for (; i + 1 < n; i += 2){
            int s0 = __shfl(sv, i);
            int s1 = __shfl(sv, i+1);
            float l0 = as1[s0*8 + h];
            float l1 = as1[s1*8 + h];
            unsigned hv0 = *(const unsigned*)(h1bf + (size_t)s0*128 + col);
            unsigned hv1 = *(const unsigned*)(h1bf + (size_t)s1*128 + col);
            float w0 = __expf(lrelu(l0 + ad));
            float w1 = __expf(lrelu(l1 + ad));
            acc0 += w0*bf2f((unsigned short)hv0) + w1*bf2f((unsigned short)hv1);
            acc1 += w0*bf2f((unsigned short)(hv0>>16)) + w1*bf2f((unsigned short)(hv1>>16));
            wsum += w0 + w1;
        }
        if (i < n){
            int s0 = __shfl(sv, i);
            float w0 = __expf(lrelu(as1[s0*8 + h] + ad));
            unsigned hv0 = *(const unsigned*)(h1bf + (size_t)s0*128 + col);
            acc0 += w0*bf2f((unsigned short)hv0);
            acc1 += w0*bf2f((unsigned short)(hv0>>16));
            wsum += w0;
        }
    }
    float inv = 1.f/(wsum + 1e-16f);
    emb1_out[(size_t)d*128 + col]     = acc0*inv + b1[col];
    emb1_out[(size_t)d*128 + col + 1] = acc1*inv + b1[col+1];
}

// ---------- GEMM2 (MFMA): h2 = bf16(elu(emb1)) @ bf16(W2), N padded to 112 ----------
__global__ __launch_bounds__(256) void gemm2_mfma(
    const float* __restrict__ emb1g /* d_out+1 */, const unsigned short* __restrict__ wt2,
    unsigned short* __restrict__ h2bf)
{
    __shared__ unsigned short Al[64*128];   // 16 KB
    __shared__ unsigned short Bl[112*128];  // 28 KB
    int t = threadIdx.x;
    int row0 = blockIdx.x*64;

    #pragma unroll
    for (int i = 0; i < 4; i++){
        int idx = (i*256 + t)*8;
        int r = idx >> 7, c = idx & 127;
        int grow = row0 + r;
        bf16x8 v;
        if (grow < N_NODES){
            const float4* p = (const float4*)(emb1g + (size_t)grow*128 + c);
            float4 f0 = p[0], f1 = p[1];
            v[0]=(__bf16)eluf(f0.x); v[1]=(__bf16)eluf(f0.y); v[2]=(__bf16)eluf(f0.z); v[3]=(__bf16)eluf(f0.w);
            v[4]=(__bf16)eluf(f1.x); v[5]=(__bf16)eluf(f1.y); v[6]=(__bf16)eluf(f1.z); v[7]=(__bf16)eluf(f1.w);
        } else {
            #pragma unroll
            for (int j = 0; j < 8; j++) v[j] = (__bf16)0.f;
        }
        int byte = (r*256 + c*2) ^ ((r&7)<<4);
        *(bf16x8*)((char*)Al + byte) = v;
    }
    // stage B: wt2 [112][128]
    for (int i = 0; i < 7; i++){
        int idx = (i*256 + t)*8;
        int n = idx >> 7, c = idx & 127;
        bf16x8 v = *(const bf16x8*)(wt2 + n*128 + c);
        int byte = (n*256 + c*2) ^ ((n&7)<<4);
        *(bf16x8*)((char*)Bl + byte) = v;
    }
    __syncthreads();

    int wv = t >> 6, l = t & 63;
    int lr = l & 15, lg = l >> 4;
    bf16x8 af[4];
    #pragma unroll
    for (int ks = 0; ks < 4; ks++){
        int r = wv*16 + lr;
        int byte = (r*256 + (ks*32 + lg*8)*2) ^ ((r&7)<<4);
        af[ks] = *(const bf16x8*)((const char*)Al + byte);
    }
    int orow_base = row0 + wv*16 + lg*4;
    #pragma unroll
    for (int nt = 0; nt < 7; nt++){
        f32x4 acc = (f32x4){0.f,0.f,0.f,0.f};
        #pragma unroll
        for (int ks = 0; ks < 4; ks++){
            int n = nt*16 + lr;
            int byte = (n*256 + (ks*32 + lg*8)*2) ^ ((n&7)<<4);
            bf16x8 bfv = *(const bf16x8*)((const char*)Bl + byte);
            acc = __builtin_amdgcn_mfma_f32_16x16x32_bf16(af[ks], bfv, acc, 0, 0, 0);
        }
        int col = nt*16 + lr;
        if (col < 100){
            #pragma unroll
            for (int r = 0; r < 4; r++){
                int grow = orow_base + r;
                if (grow < N_NODES) h2bf[(size_t)grow*100 + col] = f2bf(acc[r]);
            }
        }
    }
}

// ---------- alpha2: as2/ad2 from h2bf ----------
__global__ __launch_bounds__(256) void alpha2_kernel(
    const unsigned short* __restrict__ h2bf,
    const float* __restrict__ a_src2, const float* __restrict__ a_dst2,
    float* __restrict__ as2, float* __restrict__ ad2)
{
    int gid = blockIdx.x*256 + threadIdx.x;
    int node = gid >> 4, h = gid & 15;
    if (node >= N_NODES || h >= 10) return;
    const unsigned short* p = h2bf + (size_t)node*100 + h*10;
    float s = 0.f, d = 0.f;
    #pragma unroll
    for (int c = 0; c < 10; c++){
        float v = bf2f(p[c]);
        s += v*a_src2[h*10 + c];
        d += v*a_dst2[h*10 + c];
    }
    as2[node*10 + h] = s;
    ad2[node*10 + h] = d;
}

// ---------- agg layer2 ----------
__global__ __launch_bounds__(128) void agg2_kernel(
    const int* __restrict__ offs, const int* __restrict__ csr_src,
    const float* __restrict__ as2, const float* __restrict__ ad2,
    const unsigned short* __restrict__ h2bf, const float* __restrict__ b2,
    float* __restrict__ emb2_out)
{
    __shared__ float sval[100];
    __shared__ int sidx[128];
    int d = blockIdx.x;
    int t = threadIdx.x;
    int j = t;
    int e0 = offs[d], e1 = offs[d+1];
    int h = j/10;
    float ad = (j < 100) ? ad2[d*10 + h] : 0.f;
    float acc = 0.f, wsum = 0.f;

    for (int base = e0; base < e1; base += 128){
        int ii = base + t;
        if (ii < e1) sidx[t] = csr_src[ii];
        __syncthreads();
        int n = min(128, e1 - base);
        if (j < 100){
            int i = 0;
            for (; i + 1 < n; i += 2){
                int s0 = sidx[i], s1 = sidx[i+1];
                float l0 = as2[s0*10 + h];
                float l1 = as2[s1*10 + h];
                unsigned short v0 = h2bf[(size_t)s0*100 + j];
                unsigned short v1 = h2bf[(size_t)s1*100 + j];
                float w0 = __expf(lrelu(l0 + ad));
                float w1 = __expf(lrelu(l1 + ad));
                acc += w0*bf2f(v0) + w1*bf2f(v1);
                wsum += w0 + w1;
            }
            if (i < n){
                int s0 = sidx[i];
                float w0 = __expf(lrelu(as2[s0*10 + h] + ad));
                acc += w0*bf2f(h2bf[(size_t)s0*100 + j]);
                wsum += w0;
            }
        }
        __syncthreads();
    }
    if (j < 100) sval[j] = acc/(wsum + 1e-16f);
    __syncthreads();
    if (j < 10){
        float s = 0.f;
        #pragma unroll
        for (int hh = 0; hh < 10; hh++) s += sval[hh*10 + j];
        emb2_out[(size_t)d*10 + j] = s*0.1f + b2[j];
    }
}

// ---------- loss ----------
__global__ __launch_bounds__(256) void loss_kernel(
    const float* __restrict__ emb2, const int* __restrict__ labels,
    const int* __restrict__ mask, float* __restrict__ acc)
{
    int i = blockIdx.x*256 + threadIdx.x;
    float num = 0.f, den = 0.f;
    if (i < N_NODES && mask[i] != 0){
        const float* v = emb2 + (size_t)i*10;
        float m = v[0];
        #pragma unroll
        for (int c = 1; c < 10; c++) m = fmaxf(m, v[c]);
        float s = 0.f;
        #pragma unroll
        for (int c = 0; c < 10; c++) s += __expf(v[c]-m);
        float lse = m + __logf(s);
        num = lse - v[labels[i]];
        den = 1.f;
    }
    #pragma unroll
    for (int o = 32; o >= 1; o >>= 1){ num += __shfl_down(num, o); den += __shfl_down(den, o); }
    if ((threadIdx.x & 63) == 0){
        atomicAdd(&acc[0], num);
        atomicAdd(&acc[1], den);
    }
}

__global__ void finalize_kernel(const float* __restrict__ acc, float* __restrict__ out0){
    out0[0] = acc[0]/acc[1];
}

extern "C" void kernel_launch(void* const* d_in, const int* in_sizes, int n_in,
                              void* d_out, int out_size, void* d_ws, size_t ws_size,
                              hipStream_t stream) {
    const float* x      = (const float*)d_in[0];
    const int*   ei     = (const int*)d_in[1];
    const int*   labels = (const int*)d_in[2];
    const int*   mask   = (const int*)d_in[3];
    const float* W1     = (const float*)d_in[4];
    const float* a_src1 = (const float*)d_in[5];
    const float* a_dst1 = (const float*)d_in[6];
    const float* b1     = (const float*)d_in[7];
    const float* W2     = (const float*)d_in[8];
    const float* a_src2 = (const float*)d_in[9];
    const float* a_dst2 = (const float*)d_in[10];
    const float* b2     = (const float*)d_in[11];

    float* out  = (float*)d_out;
    float* emb1 = out + 1;                       // [N,128]
    float* emb2 = out + 1 + (size_t)N_NODES*128; // [N,10]

    unsigned short* h1bf = (unsigned short*)d_ws;              // N*128 bf16
    unsigned short* h2bf = h1bf + (size_t)N_NODES*128;         // N*100 bf16
    float* as1  = (float*)(h2bf + (size_t)N_NODES*100);
    float* ad1  = as1 + (size_t)N_NODES*8;
    float* as2  = ad1 + (size_t)N_NODES*8;
    float* ad2  = as2 + (size_t)N_NODES*10;
    float* lacc = ad2 + (size_t)N_NODES*10;  // 4 floats
    int* counts = (int*)(lacc + 4);          // N
    int* offs   = counts + N_NODES;          // N+1
    int* cursor = offs + N_NODES + 1;        // N+1
    int* csr    = cursor + N_NODES + 1;      // E
    int* exoffs = csr + N_EDGES;             // N
    int* bsums  = exoffs + N_NODES;          // NB_SCAN
    int* bpre   = bsums + NB_SCAN;           // NB_SCAN
    unsigned short* wt1 = (unsigned short*)(bpre + NB_SCAN);   // 128*128 bf16
    unsigned short* wt2 = wt1 + 128*128;                       // 112*128 bf16

    hipMemsetAsync(counts, 0, N_NODES*sizeof(int), stream);
    hipMemsetAsync(lacc, 0, 4*sizeof(float), stream);

    prep_w1<<<64, 256, 0, stream>>>(W1, wt1);
    prep_w2<<<56, 256, 0, stream>>>(W2, wt2);

    count_kernel<<<N_EDGES/256, 256, 0, stream>>>(ei, counts);
    scan_blocks_kernel<<<NB_SCAN, 1024, 0, stream>>>(counts, exoffs, bsums);
    scan_sums_kernel<<<1, 64, 0, stream>>>(bsums, bpre);
    scan_add_kernel<<<NB_SCAN, 1024, 0, stream>>>(exoffs, bpre, offs, cursor);
    scatter_kernel<<<N_EDGES/256, 256, 0, stream>>>(ei, cursor, csr);

    int gblocks = (N_NODES + 63)/64;  // 1563
    gemm1_mfma<<<gblocks, 256, 0, stream>>>(x, wt1, a_src1, a_dst1, h1bf, as1, ad1);
    agg1_kernel<<<(N_NODES + 3)/4, 256, 0, stream>>>(offs, csr, as1, ad1, h1bf, b1, emb1);
    gemm2_mfma<<<gblocks, 256, 0, stream>>>(emb1, wt2, h2bf);
    alpha2_kernel<<<(N_NODES*16 + 255)/256, 256, 0, stream>>>(h2bf, a_src2, a_dst2, as2, ad2);
    agg2_kernel<<<N_NODES, 128, 0, stream>>>(offs, csr, as2, ad2, h2bf, b2, emb2);
    loss_kernel<<<(N_NODES+255)/256, 256, 0, stream>>>(emb2, labels, mask, lacc);
    finalize_kernel<<<1, 1, 0, stream>>>(lacc, out);
}